// Round 6
// baseline (114.642 us; speedup 1.0000x reference)
//
#include <hip/hip_runtime.h>

#define NUM_CLASSES 80
constexpr int Bn = 8;
constexpr int Gn = 128;
constexpr int An = 131072;

constexpr int TB   = 256;       // threads per block (4 waves)
constexpr int PH   = 4;         // sequential anchor phases per thread
constexpr int BBLK = TB * PH;   // 1024 anchors per block

// out layout: cls (B,A,80) | reg (B,A,4) | states (B,A)
constexpr size_t CLS_OFF = 0;
constexpr size_t REG_OFF = (size_t)Bn * An * NUM_CLASSES;
constexpr size_t ST_OFF  = REG_OFF + (size_t)Bn * An * 4;

__global__ __launch_bounds__(TB, 4) void targets_kernel(
    const float* __restrict__ ann,      // (B,G,5) x1,y1,x2,y2,label
    const float* __restrict__ anchors,  // (A,4)
    float* __restrict__ out)
{
#pragma clang fp contract(off)
    const int tid  = threadIdx.x;
    const int lane = tid & 63;
    const int wv   = tid >> 6;
    const int b    = blockIdx.y;
    const int base = blockIdx.x * BBLK;

    __shared__ float4 sbox[Gn];
    __shared__ float  sarea[Gn];
    __shared__ float  slabel[Gn];

    if (tid < Gn) {
        const float* p = ann + ((size_t)b * Gn + tid) * 5;
        const float x1 = p[0], y1 = p[1], x2 = p[2], y2 = p[3];
        sbox[tid]   = make_float4(x1, y1, x2, y2);
        sarea[tid]  = (x2 - x1) * (y2 - y1);   // ref op order
        slabel[tid] = p[4];
    }

    // prefetch all phases' anchors (independent of LDS; in flight early)
    float4 av[PH];
    #pragma unroll
    for (int p = 0; p < PH; ++p)
        av[p] = *reinterpret_cast<const float4*>(
                    anchors + (size_t)(base + p * TB + tid) * 4);

    __syncthreads();   // the only barrier: boxes staged

    #pragma unroll
    for (int p = 0; p < PH; ++p) {
        const int a = base + p * TB + tid;
        const float ax1 = av[p].x, ay1 = av[p].y, ax2 = av[p].z, ay2 = av[p].w;
        const float wa = ax2 - ax1;
        const float ha = ay2 - ay1;
        const float area_a = wa * ha;      // == (ax2-ax1)*(ay2-ay1)

        // division-free argmax: keep (inter, uni) of the best box.
        // g=0 initializes (matches ref: argmax starts at index 0).
        float interB, uniB;
        {
            const float4 bv = sbox[0];
            float iw = fminf(ax2, bv.z) - fmaxf(ax1, bv.x);
            iw = fmaxf(iw, 0.0f);
            float ih = fminf(ay2, bv.w) - fmaxf(ay1, bv.y);
            ih = fmaxf(ih, 0.0f);
            interB = iw * ih;
            uniB   = (area_a + sarea[0]) - interB;
        }
        int besti = 0;

        #pragma unroll 2
        for (int g = 1; g < Gn; ++g) {
            const float4 bv = sbox[g];        // broadcast ds_read_b128
            const float area_b = sarea[g];    // broadcast ds_read_b32
            float iw = fminf(ax2, bv.z) - fmaxf(ax1, bv.x);
            iw = fmaxf(iw, 0.0f);
            float ih = fminf(ay2, bv.w) - fmaxf(ay1, bv.y);
            ih = fmaxf(ih, 0.0f);
            const float inter = iw * ih;
            const float uni = (area_a + area_b) - inter;  // > 0 always here
            // iou_g > iou_best  <=>  inter*uniB > interB*uni   (uni,uniB > 0)
            const bool upd = (inter * uniB) > (interB * uni);
            interB = upd ? inter : interB;
            uniB   = upd ? uni   : uniB;
            besti  = upd ? g     : besti;
        }

        // exact ref-order division for the winning box
        const float best = interB / fmaxf(uniB, 1e-8f);

        // states
        const float st = (best >= 0.5f) ? 1.0f : ((best < 0.4f) ? 0.0f : -1.0f);
        out[ST_OFF + (size_t)b * An + a] = st;

        // reg targets
        {
            const float4 gt = sbox[besti];
            float4 rv;
            rv.x = ((gt.x - ax1) / wa) / 0.2f;
            rv.y = ((gt.y - ay1) / ha) / 0.2f;
            rv.z = ((gt.z - ax2) / wa) / 0.2f;
            rv.w = ((gt.w - ay2) / ha) / 0.2f;
            *reinterpret_cast<float4*>(out + REG_OFF + ((size_t)b * An + a) * 4) = rv;
        }

        // cls one-hot, wave-cooperative, no barrier: this wave owns 64
        // contiguous anchors of this phase -> 1280 contiguous float4s.
        const int mylab = (st == 1.0f) ? (int)slabel[besti] : -1;
        float4* dst = reinterpret_cast<float4*>(
            out + CLS_OFF + ((size_t)b * An + base + p * TB + wv * 64) * NUM_CLASSES);
        #pragma unroll
        for (int i = 0; i < 20; ++i) {
            const int p4  = i * 64 + lane;    // 0..1279
            const int anc = p4 / 20;          // local anchor 0..63
            const int c0  = (p4 - anc * 20) * 4;
            const int lab = __shfl(mylab, anc, 64);
            float4 v;
            v.x = (c0     == lab) ? 1.0f : 0.0f;
            v.y = (c0 + 1 == lab) ? 1.0f : 0.0f;
            v.z = (c0 + 2 == lab) ? 1.0f : 0.0f;
            v.w = (c0 + 3 == lab) ? 1.0f : 0.0f;
            dst[p4] = v;
        }
    }
}

extern "C" void kernel_launch(void* const* d_in, const int* in_sizes, int n_in,
                              void* d_out, int out_size, void* d_ws, size_t ws_size,
                              hipStream_t stream) {
    const float* ann     = (const float*)d_in[0];   // (8,128,5)
    const float* anchors = (const float*)d_in[1];   // (131072,4)
    float* out = (float*)d_out;

    dim3 grid(An / BBLK, Bn, 1);   // 128 x 8 = 1024 blocks (4 per CU)
    dim3 block(TB, 1, 1);
    targets_kernel<<<grid, block, 0, stream>>>(ann, anchors, out);
}

// Round 7
// 89.558 us; speedup vs baseline: 1.2801x; 1.2801x over previous
//
#include <hip/hip_runtime.h>

#define NUM_CLASSES 80
constexpr int Bn = 8;
constexpr int Gn = 128;
constexpr int An = 131072;

constexpr int TB   = 256;   // threads per block (4 waves)
constexpr int BBLK = 512;   // anchors per block (2 per thread)

// out layout: cls (B,A,80) | reg (B,A,4) | states (B,A)
constexpr size_t CLS_OFF = 0;
constexpr size_t REG_OFF = (size_t)Bn * An * NUM_CLASSES;
constexpr size_t ST_OFF  = REG_OFF + (size_t)Bn * An * 4;

__global__ __launch_bounds__(TB, 4) void targets_kernel(
    const float* __restrict__ ann,      // (B,G,5) x1,y1,x2,y2,label
    const float* __restrict__ anchors,  // (A,4)
    float* __restrict__ out)
{
#pragma clang fp contract(off)
    const int tid  = threadIdx.x;
    const int b    = blockIdx.y;
    const int base = blockIdx.x * BBLK;
    const bool zero_first = (blockIdx.x & 1);   // odd blocks: producer role

    __shared__ float4 sbox[Gn];
    __shared__ float  slabel[Gn];
    __shared__ int    slab[BBLK];

    if (tid < Gn) {
        const float* p = ann + ((size_t)b * Gn + tid) * 5;
        sbox[tid]   = make_float4(p[0], p[1], p[2], p[3]);
        slabel[tid] = p[4];
    }
    __syncthreads();   // staging visible (nothing big outstanding)

    float4* cls_blk = reinterpret_cast<float4*>(
        out + CLS_OFF + ((size_t)b * An + base) * NUM_CLASSES);

    // Odd blocks: flood the write queue with data-independent zeros NOW.
    // Store data is a constant-zero register quad -> no vmcnt register
    // recycling hazard with the compute below; stores drain under compute.
    if (zero_first) {
        const float4 z = make_float4(0.f, 0.f, 0.f, 0.f);
        #pragma unroll
        for (int i = 0; i < (BBLK * 20) / TB; ++i)   // 40 float4s/thread
            cls_blk[tid + i * TB] = z;
    }

    // ---- compute: 2 anchors per thread, division-free argmax ----
    const int a = base + tid * 2;
    const float4 av0 = *reinterpret_cast<const float4*>(anchors + (size_t)a * 4);
    const float4 av1 = *reinterpret_cast<const float4*>(anchors + (size_t)a * 4 + 4);

    const float ax1[2] = { av0.x, av1.x };
    const float ay1[2] = { av0.y, av1.y };
    const float ax2[2] = { av0.z, av1.z };
    const float ay2[2] = { av0.w, av1.w };
    float wa[2], ha[2], area_a[2], interB[2], uniB[2];
    int besti[2];
    #pragma unroll
    for (int j = 0; j < 2; ++j) {
        wa[j] = ax2[j] - ax1[j];
        ha[j] = ay2[j] - ay1[j];
        area_a[j] = wa[j] * ha[j];          // ref op order
    }
    {   // g = 0 initializes (argmax starts at index 0)
        const float4 bv = sbox[0];
        const float area_b = (bv.z - bv.x) * (bv.w - bv.y);
        #pragma unroll
        for (int j = 0; j < 2; ++j) {
            float iw = fminf(ax2[j], bv.z) - fmaxf(ax1[j], bv.x);
            iw = fmaxf(iw, 0.0f);
            float ih = fminf(ay2[j], bv.w) - fmaxf(ay1[j], bv.y);
            ih = fmaxf(ih, 0.0f);
            interB[j] = iw * ih;
            uniB[j]   = (area_a[j] + area_b) - interB[j];
            besti[j]  = 0;
        }
    }
    #pragma unroll 2
    for (int g = 1; g < Gn; ++g) {
        const float4 bv = sbox[g];          // broadcast ds_read_b128
        const float area_b = (bv.z - bv.x) * (bv.w - bv.y);  // ref order
        #pragma unroll
        for (int j = 0; j < 2; ++j) {
            float iw = fminf(ax2[j], bv.z) - fmaxf(ax1[j], bv.x);
            iw = fmaxf(iw, 0.0f);
            float ih = fminf(ay2[j], bv.w) - fmaxf(ay1[j], bv.y);
            ih = fmaxf(ih, 0.0f);
            const float inter = iw * ih;
            const float uni = (area_a[j] + area_b) - inter;  // > 0 here
            // iou_g > iou_best  <=>  inter*uniB > interB*uni (both unions > 0)
            const bool upd = (inter * uniB[j]) > (interB[j] * uni);
            interB[j] = upd ? inter : interB[j];
            uniB[j]   = upd ? uni   : uniB[j];
            besti[j]  = upd ? g     : besti[j];
        }
    }

    float st[2];
    #pragma unroll
    for (int j = 0; j < 2; ++j) {
        const float best = interB[j] / fmaxf(uniB[j], 1e-8f);  // exact ref div
        st[j] = (best >= 0.5f) ? 1.0f : ((best < 0.4f) ? 0.0f : -1.0f);
    }
    *reinterpret_cast<float2*>(out + ST_OFF + (size_t)b * An + a) =
        make_float2(st[0], st[1]);

    #pragma unroll
    for (int j = 0; j < 2; ++j) {
        const float4 gt = sbox[besti[j]];
        float4 rv;
        rv.x = ((gt.x - ax1[j]) / wa[j]) / 0.2f;
        rv.y = ((gt.y - ay1[j]) / ha[j]) / 0.2f;
        rv.z = ((gt.z - ax2[j]) / wa[j]) / 0.2f;
        rv.w = ((gt.w - ay2[j]) / ha[j]) / 0.2f;
        *reinterpret_cast<float4*>(out + REG_OFF + ((size_t)b * An + a + j) * 4) = rv;
        slab[tid * 2 + j] = (st[j] == 1.0f) ? (int)slabel[besti[j]] : -1;
    }

    // barrier: slab visible; for odd blocks the vmcnt(0) drain also
    // guarantees the zero-stores are ordered before the patches below.
    __syncthreads();

    if (zero_first) {
        // sparse patch: one dword per positive anchor
        #pragma unroll
        for (int k = tid; k < BBLK; k += TB) {
            const int lab = slab[k];
            if (lab >= 0)
                out[CLS_OFF + ((size_t)b * An + base + k) * NUM_CLASSES + lab] = 1.0f;
        }
    } else {
        // consumer role: inline one-hot stream, fully coalesced
        #pragma unroll
        for (int i = 0; i < (BBLK * 20) / TB; ++i) {   // 40 float4s/thread
            const int p4  = tid + i * TB;              // 0..10239
            const int anc = p4 / 20;
            const int c0  = (p4 - anc * 20) * 4;
            const int lab = slab[anc];
            float4 v;
            v.x = (c0     == lab) ? 1.0f : 0.0f;
            v.y = (c0 + 1 == lab) ? 1.0f : 0.0f;
            v.z = (c0 + 2 == lab) ? 1.0f : 0.0f;
            v.w = (c0 + 3 == lab) ? 1.0f : 0.0f;
            cls_blk[p4] = v;
        }
    }
}

extern "C" void kernel_launch(void* const* d_in, const int* in_sizes, int n_in,
                              void* d_out, int out_size, void* d_ws, size_t ws_size,
                              hipStream_t stream) {
    const float* ann     = (const float*)d_in[0];   // (8,128,5)
    const float* anchors = (const float*)d_in[1];   // (131072,4)
    float* out = (float*)d_out;

    dim3 grid(An / BBLK, Bn, 1);   // 256 x 8 = 2048 blocks
    dim3 block(TB, 1, 1);
    targets_kernel<<<grid, block, 0, stream>>>(ann, anchors, out);
}